// Round 8
// baseline (7560.197 us; speedup 1.0000x reference)
//
#include <hip/hip_runtime.h>
#include <hip/hip_bf16.h>

#define BB 4096
#define TT 512
#define HH 256
#define RR 32              // batch rows per block
#define NB (BB / RR)       // 128 blocks -> 16 per XCD (halves per-XCD L2 stream)

typedef __bf16 bf16x8 __attribute__((ext_vector_type(8)));
typedef float f32x4 __attribute__((ext_vector_type(4)));

#define MFMA __builtin_amdgcn_mfma_f32_16x16x32_bf16

// Extended-K layout: K = 288 (256 h | x at k=256 | 1 at k=257 | zeros).
// 65 column-tiles (ctg 0..63 gates, 64 = heads: col0=mean,col1=logvar), 9 k-tiles.
// frag (ctg,kt): lane l, elem e = W_ext[ctg*16 + (l&15)][kt*32 + 8*(l>>4) + e]
// stored at wB[((ctg*9 + kt)*64 + l)*8 + e].
__global__ void prep_weights(const float* __restrict__ w_hh, const float* __restrict__ w_ih,
                             const float* __restrict__ b_ih, const float* __restrict__ b_hh,
                             const float* __restrict__ w_mean, const float* __restrict__ b_mean,
                             const float* __restrict__ w_logvar, const float* __restrict__ b_logvar,
                             __bf16* __restrict__ wB) {
    int idx = blockIdx.x * blockDim.x + threadIdx.x;
    if (idx >= 65 * 9 * 64) return;
    int l = idx & 63;
    int kt = (idx >> 6) % 9;
    int ctg = idx / (9 * 64);
    int col = l & 15;
    int k0 = kt * 32 + 8 * (l >> 4);
    bf16x8 v;
#pragma unroll
    for (int e = 0; e < 8; ++e) {
        int k = k0 + e;
        float f = 0.f;
        if (ctg < 64) {
            int n = ctg * 16 + col;
            if (k < 256) f = w_hh[n * HH + k];
            else if (k == 256) f = w_ih[n];
            else if (k == 257) f = b_ih[n] + b_hh[n];
        } else if (col == 0) {
            if (k < 256) f = w_mean[k];
            else if (k == 257) f = b_mean[0];
        } else if (col == 1) {
            if (k < 256) f = w_logvar[k];
            else if (k == 257) f = b_logvar[0];
        }
        v[e] = (__bf16)f;
    }
    *(bf16x8*)(wB + (size_t)idx * 8) = v;
}

// Fast activations: v_exp + v_rcp (1 ulp), no v_div expansion (no fast-math here).
__device__ __forceinline__ float sg(float v) {
    return __builtin_amdgcn_rcpf(1.f + __expf(-v));
}
__device__ __forceinline__ float th(float v) {  // NaN-safe tanh
    float e = __expf(2.f * v);
    return 1.f - 2.f * __builtin_amdgcn_rcpf(e + 1.f);
}

// ARCH-REG BUDGET (rounds 4-7): allocator grants ~128 arch VGPRs; accs go to
// AGPR. This design: wreg 32 + stream quads 32 (sA,sB) + c 16 + af 8 + misc
// ~30 = ~120 arch; acc[16]+ah[2] = 72 AGPR. R=32 rows amortizes the L2 weight
// stream over 2 row-tiles (2 MFMAs per streamed frag) and halves per-XCD L2
// traffic (16 blocks/XCD instead of 32).
__global__ __launch_bounds__(512, 1) void lstm_fused(
    const float* __restrict__ x, const float* __restrict__ eps,
    const __bf16* __restrict__ wB, float* __restrict__ out)
{
    __shared__ __align__(16) __bf16 wlds[8][12][512];   // 98304 B: kt0 (f=cc), kt1 Q0 (f=8+cc)
    __shared__ __align__(16) __bf16 hbuf[2][32][296];   // 37888 B, ping-pong, K=288 + pad
    __shared__ __align__(16) __bf16 headw[9][512];      // 9216 B
    __shared__ float obuf[3][32][8];                    // 3072 B, 8-step output batch
    // total 148480 B

    const int tid = threadIdx.x;
    const int w = tid >> 6;          // wave 0..7
    const int l = tid & 63;
    const int m0 = blockIdx.x * RR;

    for (int i = tid; i < 2 * 32 * 296; i += 512) (&hbuf[0][0][0])[i] = (__bf16)0.f;
    for (int i = tid; i < 9 * 64; i += 512) {
        int kt = i >> 6, hl = i & 63;
        *(bf16x8*)&headw[kt][hl * 8] = *(const bf16x8*)(wB + (size_t)((64 * 9 + kt) * 64 + hl) * 8);
    }

    // wave w owns ctg = w + 8p + 16g for cc = p*4+g; per-lane stream base:
    // frag(cc,kt) = wbl + (8*(cc>>2) + 16*(cc&3))*4608 + kt*512   (literal offsets)
    const __bf16* wbl = wB + (size_t)w * (9 * 64 * 8) + (size_t)l * 8;
#define FOFF(CC, KT) ((8 * ((CC) >> 2) + 16 * ((CC) & 3)) * 4608 + (KT) * 512)

    bf16x8 wreg[8];  // kt=8 (x+bias fold) per cc
#pragma unroll
    for (int cc = 0; cc < 8; ++cc) {
        wreg[cc] = *(const bf16x8*)(wbl + FOFF(cc, 8));
        *(bf16x8*)&wlds[w][cc][l * 8] = *(const bf16x8*)(wbl + FOFF(cc, 0));
        if (cc < 4)
            *(bf16x8*)&wlds[w][8 + cc][l * 8] = *(const bf16x8*)(wbl + FOFF(cc, 1));
    }

    __syncthreads();
    if (tid < RR) {
        hbuf[0][tid][257] = (__bf16)1.0f;
        hbuf[1][tid][257] = (__bf16)1.0f;
        hbuf[1][tid][256] = (__bf16)x[(size_t)(m0 + tid) * TT];  // x_0 (rb of t=0 is buf 1)
    }

    const int arow = l & 15;
    const int ako = 8 * (l >> 4);
    const int r0 = (l >> 4) * 4;
    const bool headwave = (w == 0);
    float c[16];
#pragma unroll
    for (int i = 0; i < 16; ++i) c[i] = 0.f;

    __syncthreads();

#define LB(F) (*(const bf16x8*)&wlds[w][F][l * 8])
#define LQ(D, KT, P)                                          \
    do {                                                      \
        D[0] = *(const bf16x8*)(wbl + FOFF((P)*4 + 0, KT));   \
        D[1] = *(const bf16x8*)(wbl + FOFF((P)*4 + 1, KT));   \
        D[2] = *(const bf16x8*)(wbl + FOFF((P)*4 + 2, KT));   \
        D[3] = *(const bf16x8*)(wbl + FOFF((P)*4 + 3, KT));   \
    } while (0)
#define AFLOAD(KT)                                                    \
    af0 = *(const bf16x8*)&hbuf[rb][arow][(KT) * 32 + ako];           \
    af1 = *(const bf16x8*)&hbuf[rb][16 + arow][(KT) * 32 + ako];
#define HMF(KT)                                                       \
    if (dh) {                                                         \
        bf16x8 hw_ = *(const bf16x8*)&headw[KT][l * 8];               \
        ah[0] = MFMA(af0, hw_, ah[0], 0, 0, 0);                       \
        ah[1] = MFMA(af1, hw_, ah[1], 0, 0, 0);                       \
    }
// acc slot = p*8 + g*2 + at
#define QUAD(P, B0, B1, B2, B3)                                       \
    acc[(P)*8 + 0] = MFMA(af0, B0, acc[(P)*8 + 0], 0, 0, 0);          \
    acc[(P)*8 + 1] = MFMA(af1, B0, acc[(P)*8 + 1], 0, 0, 0);          \
    acc[(P)*8 + 2] = MFMA(af0, B1, acc[(P)*8 + 2], 0, 0, 0);          \
    acc[(P)*8 + 3] = MFMA(af1, B1, acc[(P)*8 + 3], 0, 0, 0);          \
    acc[(P)*8 + 4] = MFMA(af0, B2, acc[(P)*8 + 4], 0, 0, 0);          \
    acc[(P)*8 + 5] = MFMA(af1, B2, acc[(P)*8 + 5], 0, 0, 0);          \
    acc[(P)*8 + 6] = MFMA(af0, B3, acc[(P)*8 + 6], 0, 0, 0);          \
    acc[(P)*8 + 7] = MFMA(af1, B3, acc[(P)*8 + 7], 0, 0, 0);
#define QUADZ(P, B0, B1, B2, B3)                                      \
    acc[(P)*8 + 0] = MFMA(af0, B0, Z, 0, 0, 0);                       \
    acc[(P)*8 + 1] = MFMA(af1, B0, Z, 0, 0, 0);                       \
    acc[(P)*8 + 2] = MFMA(af0, B1, Z, 0, 0, 0);                       \
    acc[(P)*8 + 3] = MFMA(af1, B1, Z, 0, 0, 0);                       \
    acc[(P)*8 + 4] = MFMA(af0, B2, Z, 0, 0, 0);                       \
    acc[(P)*8 + 5] = MFMA(af1, B2, Z, 0, 0, 0);                       \
    acc[(P)*8 + 6] = MFMA(af0, B3, Z, 0, 0, 0);                       \
    acc[(P)*8 + 7] = MFMA(af1, B3, Z, 0, 0, 0);

    for (int t = 0; t < TT; ++t) {
        const int pb = t & 1, rb = pb ^ 1;
        const bool dh = headwave && (t >= 1);

        float xn = 0.f;
        if (tid < RR && t + 1 < TT) xn = x[(size_t)(m0 + tid) * TT + (t + 1)];
        float ev[8];
#pragma unroll
        for (int k = 0; k < 8; ++k) ev[k] = 0.f;
        if (dh && (l & 15) == 0) {
#pragma unroll
            for (int k = 0; k < 8; ++k)
                ev[k] = eps[(size_t)(m0 + (k >> 2) * 16 + r0 + (k & 3)) * TT + (t - 1)];
        }

        bf16x8 sA[4], sB[4], af0, af1;
        f32x4 acc[16], ah[2];
        const f32x4 Z = {0.f, 0.f, 0.f, 0.f};
        ah[0] = Z; ah[1] = Z;

        // 2-deep quad rotation: issue order == consume order
        LQ(sA, 1, 1); LQ(sB, 2, 0);

        AFLOAD(0); HMF(0);                       // kt0 from LDS, accs init via Z
        QUADZ(0, LB(0), LB(1), LB(2), LB(3));
        QUADZ(1, LB(4), LB(5), LB(6), LB(7));

        AFLOAD(8); HMF(8);                       // kt8 (x+bias) from regs
        QUAD(0, wreg[0], wreg[1], wreg[2], wreg[3]);
        QUAD(1, wreg[4], wreg[5], wreg[6], wreg[7]);

        AFLOAD(1); HMF(1);
        QUAD(0, LB(8), LB(9), LB(10), LB(11));   // kt1 Q0 from LDS
        QUAD(1, sA[0], sA[1], sA[2], sA[3]); LQ(sA, 2, 1);

        AFLOAD(2); HMF(2);
        QUAD(0, sB[0], sB[1], sB[2], sB[3]); LQ(sB, 3, 0);
        QUAD(1, sA[0], sA[1], sA[2], sA[3]); LQ(sA, 3, 1);

        AFLOAD(3); HMF(3);
        QUAD(0, sB[0], sB[1], sB[2], sB[3]); LQ(sB, 4, 0);
        QUAD(1, sA[0], sA[1], sA[2], sA[3]); LQ(sA, 4, 1);

        AFLOAD(4); HMF(4);
        QUAD(0, sB[0], sB[1], sB[2], sB[3]); LQ(sB, 5, 0);
        QUAD(1, sA[0], sA[1], sA[2], sA[3]); LQ(sA, 5, 1);

        AFLOAD(5); HMF(5);
        QUAD(0, sB[0], sB[1], sB[2], sB[3]); LQ(sB, 6, 0);
        QUAD(1, sA[0], sA[1], sA[2], sA[3]); LQ(sA, 6, 1);

        AFLOAD(6); HMF(6);
        QUAD(0, sB[0], sB[1], sB[2], sB[3]); LQ(sB, 7, 0);
        QUAD(1, sA[0], sA[1], sA[2], sA[3]); LQ(sA, 7, 1);

        AFLOAD(7); HMF(7);
        QUAD(0, sB[0], sB[1], sB[2], sB[3]);
        QUAD(1, sA[0], sA[1], sA[2], sA[3]);

        // ---- heads epilogue for h_{t-1} (wave 0): biases folded in ----
        if (dh) {
            const int slot = (t - 1) & 7;
#pragma unroll
            for (int at = 0; at < 2; ++at)
#pragma unroll
            for (int j = 0; j < 4; ++j) {
                float mv = ah[at][j];
                float lvn = __shfl(mv, (l & 48) | 1);  // col-1 lane = logvar
                if ((l & 15) == 0) {
                    float lv = fminf(fmaxf(lvn, -10.f), 2.f);
                    const int row = at * 16 + r0 + j;
                    obuf[0][row][slot] = mv + __expf(0.5f * lv) * ev[at * 4 + j];
                    obuf[1][row][slot] = mv;
                    obuf[2][row][slot] = lv;
                }
            }
        }

        // ---- elementwise LSTM cell: 16 cells/thread, all in registers ----
        {
            const int ub = 16 * w + arow;
#pragma unroll
            for (int p = 0; p < 2; ++p) {
                const int u = ub + 128 * p;
#pragma unroll
                for (int at = 0; at < 2; ++at)
#pragma unroll
                for (int j = 0; j < 4; ++j) {
                    const int ci = p * 8 + at * 4 + j;
                    float ia = sg(acc[p * 8 + 0 + at][j]);
                    float fa = sg(acc[p * 8 + 2 + at][j]);
                    float ga = th(acc[p * 8 + 4 + at][j]);
                    float oa = sg(acc[p * 8 + 6 + at][j]);
                    float cn = fa * c[ci] + ia * ga;
                    c[ci] = cn;
                    hbuf[pb][at * 16 + r0 + j][u] = (__bf16)(oa * th(cn));
                }
            }
        }
        if (tid < RR && t + 1 < TT) hbuf[pb][tid][256] = (__bf16)xn;  // x_{t+1}

        // ---- coalesced output flush every 8 steps ----
        if ((t & 7) == 0 && t > 0) {
            __syncthreads();
            if (tid < 192) {
                const int o = tid >> 6, rr2 = (tid & 63) >> 1, q = tid & 1;
                f32x4 v = *(const f32x4*)&obuf[o][rr2][q * 4];
                *(f32x4*)(out + (size_t)o * BB * TT + (size_t)(m0 + rr2) * TT + (t - 8) + q * 4) = v;
            }
        }
        __syncthreads();
    }

    // ---- tail: head for t = TT-1 (h in hbuf[1]) + final flush ----
    {
        if (headwave) {
            f32x4 ah[2];
            ah[0] = (f32x4){0.f, 0.f, 0.f, 0.f}; ah[1] = ah[0];
            float ev[8];
#pragma unroll
            for (int k = 0; k < 8; ++k) ev[k] = 0.f;
            if ((l & 15) == 0) {
#pragma unroll
                for (int k = 0; k < 8; ++k)
                    ev[k] = eps[(size_t)(m0 + (k >> 2) * 16 + r0 + (k & 3)) * TT + (TT - 1)];
            }
#pragma unroll
            for (int kt = 0; kt < 9; ++kt) {
                bf16x8 af0 = *(const bf16x8*)&hbuf[1][arow][kt * 32 + ako];
                bf16x8 af1 = *(const bf16x8*)&hbuf[1][16 + arow][kt * 32 + ako];
                bf16x8 hw_ = *(const bf16x8*)&headw[kt][l * 8];
                ah[0] = MFMA(af0, hw_, ah[0], 0, 0, 0);
                ah[1] = MFMA(af1, hw_, ah[1], 0, 0, 0);
            }
#pragma unroll
            for (int at = 0; at < 2; ++at)
#pragma unroll
            for (int j = 0; j < 4; ++j) {
                float mv = ah[at][j];
                float lvn = __shfl(mv, (l & 48) | 1);
                if ((l & 15) == 0) {
                    float lv = fminf(fmaxf(lvn, -10.f), 2.f);
                    const int row = at * 16 + r0 + j;
                    obuf[0][row][7] = mv + __expf(0.5f * lv) * ev[at * 4 + j];
                    obuf[1][row][7] = mv;
                    obuf[2][row][7] = lv;
                }
            }
        }
        __syncthreads();
        if (tid < 192) {
            const int o = tid >> 6, rr2 = (tid & 63) >> 1, q = tid & 1;
            f32x4 v = *(const f32x4*)&obuf[o][rr2][q * 4];
            *(f32x4*)(out + (size_t)o * BB * TT + (size_t)(m0 + rr2) * TT + (TT - 8) + q * 4) = v;
        }
    }
}

extern "C" void kernel_launch(void* const* d_in, const int* in_sizes, int n_in,
                              void* d_out, int out_size, void* d_ws, size_t ws_size,
                              hipStream_t stream) {
    const float* x = (const float*)d_in[0];
    const float* eps = (const float*)d_in[1];
    const float* w_ih = (const float*)d_in[2];
    const float* w_hh = (const float*)d_in[3];
    const float* b_ih = (const float*)d_in[4];
    const float* b_hh = (const float*)d_in[5];
    const float* w_mean = (const float*)d_in[6];
    const float* b_mean = (const float*)d_in[7];
    const float* w_logvar = (const float*)d_in[8];
    const float* b_logvar = (const float*)d_in[9];

    __bf16* wB = (__bf16*)d_ws;  // 585 KB extended fragment-ordered bf16 weights

    prep_weights<<<(65 * 9 * 64 + 255) / 256, 256, 0, stream>>>(
        w_hh, w_ih, b_ih, b_hh, w_mean, b_mean, w_logvar, b_logvar, wB);
    lstm_fused<<<NB, 512, 0, stream>>>(x, eps, wB, (float*)d_out);
}

// Round 9
// 1596.832 us; speedup vs baseline: 4.7345x; 4.7345x over previous
//
#include <hip/hip_runtime.h>
#include <hip/hip_bf16.h>

#define BB 4096
#define TT 512
#define HH 256

typedef __bf16 bf16x8 __attribute__((ext_vector_type(8)));
typedef __bf16 bf16x4 __attribute__((ext_vector_type(4)));
typedef float f32x4 __attribute__((ext_vector_type(4)));

#define MFMA __builtin_amdgcn_mfma_f32_16x16x32_bf16

// Reorder w_hh [1024][256] fp32 -> bf16 fragment-ordered buffer:
// frag (ctg,kt), lane l, elem e = w_hh[ctg*16 + (l&15)][kt*32 + 8*(l>>4) + e]
// stored at wB[((ctg*8+kt)*64 + l)*8 + e] (1 KB per frag, lane-coalesced).
__global__ void prep_weights(const float* __restrict__ w_hh, __bf16* __restrict__ wB) {
    int idx = blockIdx.x * blockDim.x + threadIdx.x;
    if (idx >= 64 * 8 * 64) return;
    int l = idx & 63;
    int kt = (idx >> 6) & 7;
    int ctg = idx >> 9;
    int n = ctg * 16 + (l & 15);
    int k0 = kt * 32 + 8 * (l >> 4);
    const float* src = w_hh + n * HH + k0;
    __bf16* dst = wB + (size_t)idx * 8;
#pragma unroll
    for (int e = 0; e < 8; ++e) dst[e] = (__bf16)src[e];
}

// Fast activations via v_rcp (1 inst) instead of v_div (~9 inst). NaN-safe.
__device__ __forceinline__ float sg(float v) {
    return __builtin_amdgcn_rcpf(1.f + __expf(-v));
}
__device__ __forceinline__ float th(float v) {
    float e = __expf(2.f * v);
    return 1.f - 2.f * __builtin_amdgcn_rcpf(e + 1.f);
}

// REGISTER LAW (rounds 4-8): allocator grants <=128 arch VGPRs; overflow goes
// to MEMORY scratch (FETCH explodes), not AGPR. Budget here: wreg 32 + stream
// in-flight 40 (2x5 frags) + c 8 + af 4 + pc 10 + misc ~20 = ~114 arch.
// Residency: wreg=cc0 (8 frags), wlds=cc1,cc2 (16 frags, 128 KB), stream
// cc3..7 (40 frags) double-buffered one kt-block ahead; kt0 group prefetched
// across the barrier under the previous step's elementwise phase.
__global__ __launch_bounds__(512, 1) void lstm_fused(
    const float* __restrict__ x, const float* __restrict__ eps,
    const float* __restrict__ w_ih, const float* __restrict__ b_ih,
    const float* __restrict__ b_hh, const float* __restrict__ w_mean,
    const float* __restrict__ b_mean, const float* __restrict__ w_logvar,
    const float* __restrict__ b_logvar, const __bf16* __restrict__ wB,
    float* __restrict__ out)
{
    __shared__ __align__(16) __bf16 wlds[8][16][512];   // 131072 B: [w][kt]=cc1, [w][8+kt]=cc2
    __shared__ __align__(16) __bf16 hbuf[2][16][264];   // 16896 B, ping-pong
    __shared__ __align__(16) __bf16 headw[8][512];      // 8192 B
    __shared__ float obuf[3][16][16];                   // 3072 B
    __shared__ __align__(8) __bf16 wib[256][4];         // 2048 B: w_ih per gate
    __shared__ __align__(8) __bf16 bib[256][4];         // 2048 B: b_ih+b_hh per gate
    __shared__ float xb[2][16];                         // 128 B
    // total 163456 B (<= 163840)

    const int tid = threadIdx.x;
    const int w = tid >> 6;          // wave 0..7
    const int l = tid & 63;
    const int m0 = blockIdx.x * 16;

    for (int i = tid; i < 2 * 16 * 264; i += 512) (&hbuf[0][0][0])[i] = (__bf16)0.f;
    for (int i = tid; i < 256; i += 512) {
#pragma unroll
        for (int g = 0; g < 4; ++g) {
            wib[i][g] = (__bf16)w_ih[g * 256 + i];
            bib[i][g] = (__bf16)(b_ih[g * 256 + i] + b_hh[g * 256 + i]);
        }
    }
    // head column-tile: col 0 = w_mean, col 1 = w_logvar, cols 2-15 zero
    {
        int kt = tid >> 6, hl = tid & 63;
        int col = hl & 15;
        int k0 = kt * 32 + 8 * (hl >> 4);
        bf16x8 hw;
#pragma unroll
        for (int e = 0; e < 8; ++e) {
            float v = 0.f;
            if (col == 0) v = w_mean[k0 + e];
            else if (col == 1) v = w_logvar[k0 + e];
            hw[e] = (__bf16)v;
        }
        *(bf16x8*)&headw[kt][hl * 8] = hw;
    }

    // wave w owns ctg = w + 8p + 16g for cc = p*4+g (all 4 gates of its units)
    // wreg: cc0 (ctg=w) kt0..7 ; wlds: cc1 (w+16), cc2 (w+32)
    bf16x8 wreg[8];
#pragma unroll
    for (int kt = 0; kt < 8; ++kt) {
        wreg[kt] = *(const bf16x8*)(wB + ((size_t)((w) * 8 + kt) * 64 + l) * 8);
        *(bf16x8*)&wlds[w][kt][l * 8] =
            *(const bf16x8*)(wB + ((size_t)((w + 16) * 8 + kt) * 64 + l) * 8);
        *(bf16x8*)&wlds[w][8 + kt][l * 8] =
            *(const bf16x8*)(wB + ((size_t)((w + 32) * 8 + kt) * 64 + l) * 8);
    }

    // streamed cc3..7 -> ctg {w+48, w+8, w+24, w+40, w+56}; anchor at kt=4 so
    // kt offsets (kt-4)*1024 B are all within the 13-bit signed immediate.
    const __bf16* pc0 = wB + ((size_t)((w + 48) * 8 + 4) * 64 + l) * 8;
    const __bf16* pc1 = wB + ((size_t)((w +  8) * 8 + 4) * 64 + l) * 8;
    const __bf16* pc2 = wB + ((size_t)((w + 24) * 8 + 4) * 64 + l) * 8;
    const __bf16* pc3 = wB + ((size_t)((w + 40) * 8 + 4) * 64 + l) * 8;
    const __bf16* pc4 = wB + ((size_t)((w + 56) * 8 + 4) * 64 + l) * 8;
#define LQK(D, KT)                                      \
    do {                                                \
        D[0] = *(const bf16x8*)(pc0 + ((KT) - 4) * 512);\
        D[1] = *(const bf16x8*)(pc1 + ((KT) - 4) * 512);\
        D[2] = *(const bf16x8*)(pc2 + ((KT) - 4) * 512);\
        D[3] = *(const bf16x8*)(pc3 + ((KT) - 4) * 512);\
        D[4] = *(const bf16x8*)(pc4 + ((KT) - 4) * 512);\
    } while (0)

    __syncthreads();
    if (tid < 16) xb[0][tid] = x[(size_t)(m0 + tid) * TT];

    const float bm = b_mean[0], blv = b_logvar[0];
    const int arow = l & 15;
    const int ako = 8 * (l >> 4);
    const int r0 = (l >> 4) * 4;
    const bool headwave = (w == 0);
    float c[8];
#pragma unroll
    for (int i = 0; i < 8; ++i) c[i] = 0.f;

    bf16x8 sb[5], tb[5];
    LQK(sb, 0);  // kt0 group for t=0 (in flight across the init barrier)
    __syncthreads();

#define KTEVEN(KT)                                                             \
    do {                                                                       \
        bf16x8 af = *(const bf16x8*)&hbuf[rb][arow][(KT) * 32 + ako];          \
        LQK(tb, (KT) + 1);                                                     \
        accs[0] = MFMA(af, wreg[KT], accs[0], 0, 0, 0);                        \
        accs[1] = MFMA(af, *(const bf16x8*)&wlds[w][KT][l * 8], accs[1], 0,0,0);\
        accs[2] = MFMA(af, *(const bf16x8*)&wlds[w][8 + (KT)][l * 8], accs[2], 0,0,0);\
        accs[3] = MFMA(af, sb[0], accs[3], 0, 0, 0);                           \
        accs[4] = MFMA(af, sb[1], accs[4], 0, 0, 0);                           \
        accs[5] = MFMA(af, sb[2], accs[5], 0, 0, 0);                           \
        accs[6] = MFMA(af, sb[3], accs[6], 0, 0, 0);                           \
        accs[7] = MFMA(af, sb[4], accs[7], 0, 0, 0);                           \
        if (dh) ah = MFMA(af, *(const bf16x8*)&headw[KT][l * 8], ah, 0, 0, 0); \
    } while (0)
#define KTODD(KT, NXT)                                                         \
    do {                                                                       \
        bf16x8 af = *(const bf16x8*)&hbuf[rb][arow][(KT) * 32 + ako];          \
        LQK(sb, NXT);                                                          \
        accs[0] = MFMA(af, wreg[KT], accs[0], 0, 0, 0);                        \
        accs[1] = MFMA(af, *(const bf16x8*)&wlds[w][KT][l * 8], accs[1], 0,0,0);\
        accs[2] = MFMA(af, *(const bf16x8*)&wlds[w][8 + (KT)][l * 8], accs[2], 0,0,0);\
        accs[3] = MFMA(af, tb[0], accs[3], 0, 0, 0);                           \
        accs[4] = MFMA(af, tb[1], accs[4], 0, 0, 0);                           \
        accs[5] = MFMA(af, tb[2], accs[5], 0, 0, 0);                           \
        accs[6] = MFMA(af, tb[3], accs[6], 0, 0, 0);                           \
        accs[7] = MFMA(af, tb[4], accs[7], 0, 0, 0);                           \
        if (dh) ah = MFMA(af, *(const bf16x8*)&headw[KT][l * 8], ah, 0, 0, 0); \
    } while (0)

    for (int t = 0; t < TT; ++t) {
        const int pb = t & 1, rb = pb ^ 1;
        const bool dh = headwave && (t >= 1);

        float xn = 0.f;
        if (tid < 16 && t + 1 < TT) xn = x[(size_t)(m0 + tid) * TT + (t + 1)];
        float ev[4] = {0.f, 0.f, 0.f, 0.f};
        if (dh && arow == 0) {
#pragma unroll
            for (int j = 0; j < 4; ++j) ev[j] = eps[(size_t)(m0 + r0 + j) * TT + (t - 1)];
        }

        f32x4 accs[8];
#pragma unroll
        for (int cc = 0; cc < 8; ++cc) accs[cc] = (f32x4){0.f, 0.f, 0.f, 0.f};
        f32x4 ah = {0.f, 0.f, 0.f, 0.f};

        KTEVEN(0);        // consumes sb(kt0), prefetches tb(kt1)
        KTODD(1, 2);      // consumes tb,     prefetches sb(kt2)
        KTEVEN(2);
        KTODD(3, 4);
        KTEVEN(4);
        KTODD(5, 6);
        KTEVEN(6);
        KTODD(7, 0);      // prefetches sb(kt0) for the NEXT step (weights static)

        // ---- heads epilogue for h_{t-1} (wave 0) ----
        if (dh) {
            const int slot = (t - 1) & 15;
#pragma unroll
            for (int j = 0; j < 4; ++j) {
                float lvn = __shfl(ah[j], (l & 48) | 1);  // col-1 lane = logvar
                if (arow == 0) {
                    float mean = ah[j] + bm;
                    float lv = fminf(fmaxf(lvn + blv, -10.f), 2.f);
                    obuf[0][r0 + j][slot] = mean + __expf(0.5f * lv) * ev[j];
                    obuf[1][r0 + j][slot] = mean;
                    obuf[2][r0 + j][slot] = lv;
                }
            }
        }

        // ---- elementwise LSTM cell: accs[p*4+g][j] = gate g, unit col, row r0+j ----
        {
            float xv[4];
#pragma unroll
            for (int j = 0; j < 4; ++j) xv[j] = xb[t & 1][r0 + j];
#pragma unroll
            for (int p = 0; p < 2; ++p) {
                const int u = 128 * p + 16 * w + arow;
                bf16x4 wv = *(const bf16x4*)&wib[u][0];
                bf16x4 bv = *(const bf16x4*)&bib[u][0];
                const float wi0 = (float)wv[0], wi1 = (float)wv[1],
                            wi2 = (float)wv[2], wi3 = (float)wv[3];
                const float bi0 = (float)bv[0], bi1 = (float)bv[1],
                            bi2 = (float)bv[2], bi3 = (float)bv[3];
#pragma unroll
                for (int j = 0; j < 4; ++j) {
                    float gi = accs[p * 4 + 0][j] + xv[j] * wi0 + bi0;
                    float gf = accs[p * 4 + 1][j] + xv[j] * wi1 + bi1;
                    float gg = accs[p * 4 + 2][j] + xv[j] * wi2 + bi2;
                    float go = accs[p * 4 + 3][j] + xv[j] * wi3 + bi3;
                    float ia = sg(gi), fa = sg(gf), ga = th(gg), oa = sg(go);
                    float cn = fa * c[p * 4 + j] + ia * ga;
                    c[p * 4 + j] = cn;
                    hbuf[pb][r0 + j][u] = (__bf16)(oa * th(cn));
                }
            }
        }
        if (tid < 16 && t + 1 < TT) xb[(t + 1) & 1][tid] = xn;

        // ---- coalesced output flush every 16 steps ----
        if ((t & 15) == 0 && t > 0) {
            __syncthreads();  // wave0's obuf writes -> flushing waves
            if (tid < 192) {
                const int o = tid >> 6, rr = (tid >> 2) & 15, q = tid & 3;
                f32x4 v = *(const f32x4*)&obuf[o][rr][q * 4];
                *(f32x4*)(out + (size_t)o * BB * TT + (size_t)(m0 + rr) * TT + (t - 16) + q * 4) = v;
            }
        }
        __syncthreads();
    }

    // ---- tail: head for t = TT-1 (h in hbuf[1]) + final flush ----
    {
        if (headwave) {
            f32x4 ah = {0.f, 0.f, 0.f, 0.f};
            float ev[4] = {0.f, 0.f, 0.f, 0.f};
            if (arow == 0) {
#pragma unroll
                for (int j = 0; j < 4; ++j) ev[j] = eps[(size_t)(m0 + r0 + j) * TT + (TT - 1)];
            }
#pragma unroll
            for (int kt = 0; kt < 8; ++kt) {
                bf16x8 af = *(const bf16x8*)&hbuf[1][arow][kt * 32 + ako];
                ah = MFMA(af, *(const bf16x8*)&headw[kt][l * 8], ah, 0, 0, 0);
            }
#pragma unroll
            for (int j = 0; j < 4; ++j) {
                float lvn = __shfl(ah[j], (l & 48) | 1);
                if (arow == 0) {
                    float mean = ah[j] + bm;
                    float lv = fminf(fmaxf(lvn + blv, -10.f), 2.f);
                    obuf[0][r0 + j][15] = mean + __expf(0.5f * lv) * ev[j];
                    obuf[1][r0 + j][15] = mean;
                    obuf[2][r0 + j][15] = lv;
                }
            }
        }
        __syncthreads();
        if (tid < 192) {
            const int o = tid >> 6, rr = (tid >> 2) & 15, q = tid & 3;
            f32x4 v = *(const f32x4*)&obuf[o][rr][q * 4];
            *(f32x4*)(out + (size_t)o * BB * TT + (size_t)(m0 + rr) * TT + (TT - 16) + q * 4) = v;
        }
    }
#undef KTEVEN
#undef KTODD
#undef LQK
}

extern "C" void kernel_launch(void* const* d_in, const int* in_sizes, int n_in,
                              void* d_out, int out_size, void* d_ws, size_t ws_size,
                              hipStream_t stream) {
    const float* x = (const float*)d_in[0];
    const float* eps = (const float*)d_in[1];
    const float* w_ih = (const float*)d_in[2];
    const float* w_hh = (const float*)d_in[3];
    const float* b_ih = (const float*)d_in[4];
    const float* b_hh = (const float*)d_in[5];
    const float* w_mean = (const float*)d_in[6];
    const float* b_mean = (const float*)d_in[7];
    const float* w_logvar = (const float*)d_in[8];
    const float* b_logvar = (const float*)d_in[9];

    __bf16* wB = (__bf16*)d_ws;  // 512 KB fragment-ordered bf16 weights

    prep_weights<<<128, 256, 0, stream>>>(w_hh, wB);
    lstm_fused<<<256, 512, 0, stream>>>(x, eps, w_ih, b_ih, b_hh, w_mean, b_mean,
                                        w_logvar, b_logvar, wB, (float*)d_out);
}

// Round 10
// 1425.380 us; speedup vs baseline: 5.3040x; 1.1203x over previous
//
#include <hip/hip_runtime.h>
#include <hip/hip_bf16.h>

#define BB 4096
#define TT 512
#define HH 256

typedef __bf16 bf16x8 __attribute__((ext_vector_type(8)));
typedef __bf16 bf16x4 __attribute__((ext_vector_type(4)));
typedef float f32x4 __attribute__((ext_vector_type(4)));
typedef long fp8frag;  // 8 x e4m3 in 2 VGPRs

#define MFMA_BF16 __builtin_amdgcn_mfma_f32_16x16x32_bf16
#define MFMA_FP8  __builtin_amdgcn_mfma_f32_16x16x32_fp8_fp8

// w_hh [1024][256] fp32 -> fp8 e4m3 (x64 scale) fragment-ordered buffer:
// frag (ctg,kt), lane l, elem e = 64*w_hh[ctg*16 + (l&15)][kt*32 + 8*(l>>4) + e]
// at wB8[((ctg*8+kt)*64 + l)*8 + e]  (512 B per frag, 256 KB total).
__global__ void prep_weights8(const float* __restrict__ w_hh, char* __restrict__ wB8) {
    int idx = blockIdx.x * blockDim.x + threadIdx.x;
    if (idx >= 64 * 8 * 64) return;
    int l = idx & 63;
    int kt = (idx >> 6) & 7;
    int ctg = idx >> 9;
    int n = ctg * 16 + (l & 15);
    int k0 = kt * 32 + 8 * (l >> 4);
    const float* src = w_hh + n * HH + k0;
    float f[8];
#pragma unroll
    for (int e = 0; e < 8; ++e) f[e] = src[e] * 64.f;
    int lo = __builtin_amdgcn_cvt_pk_fp8_f32(f[0], f[1], 0, false) |
             (__builtin_amdgcn_cvt_pk_fp8_f32(f[2], f[3], 0, false) << 16);
    int hi = __builtin_amdgcn_cvt_pk_fp8_f32(f[4], f[5], 0, false) |
             (__builtin_amdgcn_cvt_pk_fp8_f32(f[6], f[7], 0, false) << 16);
    int2 v; v.x = lo; v.y = hi;
    *(int2*)(wB8 + (size_t)idx * 8) = v;
}

// Fast activations via v_rcp (1 inst). NaN-safe.
__device__ __forceinline__ float sg(float v) {
    return __builtin_amdgcn_rcpf(1.f + __expf(-v));
}
__device__ __forceinline__ float th(float v) {
    float e = __expf(2.f * v);
    return 1.f - 2.f * __builtin_amdgcn_rcpf(e + 1.f);
}

// REGISTER LAW (r4-r9): hard grant of 128 unified regs/wave; overflow -> memory
// scratch (FETCH explodes). fp8 weights (256 KB) let 5/8 ctgs be resident:
// wreg 2 ctg (32 regs) + LDS 3 ctg (96 KB) + stream 3 ctg (12 KB/step, ~220cyc
// L2 - trivially hidden). Heads stay FULLY bf16 (logvar error is amplified by
// exp(0.5lv)*eps; only the recurrent gate path sees fp8). Scales: w x64, h x16,
// acc descale 2^-10 folded into the gate FMA.
__global__ __launch_bounds__(512, 1) void lstm_fused(
    const float* __restrict__ x, const float* __restrict__ eps,
    const float* __restrict__ w_ih, const float* __restrict__ b_ih,
    const float* __restrict__ b_hh, const float* __restrict__ w_mean,
    const float* __restrict__ b_mean, const float* __restrict__ w_logvar,
    const float* __restrict__ b_logvar, const char* __restrict__ wB8,
    float* __restrict__ out)
{
    __shared__ __align__(16) char wlds8[8][24][512];    // 98304 B: cc2,3,4 per wave
    __shared__ __align__(16) __bf16 hbuf[2][16][264];   // 16896 B: bf16 h (heads)
    __shared__ __align__(16) char hbuf8[2][16][296];    // 9472 B: fp8 h*16 (gates)
    __shared__ __align__(16) __bf16 headw[8][512];      // 8192 B
    __shared__ float obuf[3][16][16];                   // 3072 B
    __shared__ __align__(8) __bf16 wib[256][4];         // 2048 B
    __shared__ __align__(8) __bf16 bib[256][4];         // 2048 B
    __shared__ float xb[2][16];                         // 128 B
    // total 140160 B

    const int tid = threadIdx.x;
    const int w = tid >> 6;          // wave 0..7
    const int l = tid & 63;
    const int m0 = blockIdx.x * 16;

    for (int i = tid; i < 2 * 16 * 264; i += 512) (&hbuf[0][0][0])[i] = (__bf16)0.f;
    for (int i = tid; i < 2 * 16 * 296; i += 512) (&hbuf8[0][0][0])[i] = 0;
    for (int i = tid; i < 256; i += 512) {
#pragma unroll
        for (int g = 0; g < 4; ++g) {
            wib[i][g] = (__bf16)w_ih[g * 256 + i];
            bib[i][g] = (__bf16)(b_ih[g * 256 + i] + b_hh[g * 256 + i]);
        }
    }
    // head column-tile (bf16): col 0 = w_mean, col 1 = w_logvar, rest zero
    {
        int kt = tid >> 6, hl = tid & 63;
        int col = hl & 15;
        int k0 = kt * 32 + 8 * (hl >> 4);
        bf16x8 hw;
#pragma unroll
        for (int e = 0; e < 8; ++e) {
            float v = 0.f;
            if (col == 0) v = w_mean[k0 + e];
            else if (col == 1) v = w_logvar[k0 + e];
            hw[e] = (__bf16)v;
        }
        *(bf16x8*)&headw[kt][hl * 8] = hw;
    }

    // wave w owns ctg = w + 8p + 16g for cc = p*4+g.
    // wreg: cc0 (w), cc1 (w+16); LDS: cc2 (w+32), cc3 (w+48), cc4 (w+8);
    // stream: cc5 (w+24), cc6 (w+40), cc7 (w+56).
    fp8frag wreg8[16];
#pragma unroll
    for (int kt = 0; kt < 8; ++kt) {
        wreg8[kt]     = *(const fp8frag*)(wB8 + ((size_t)((w)      * 8 + kt) * 64 + l) * 8);
        wreg8[8 + kt] = *(const fp8frag*)(wB8 + ((size_t)((w + 16) * 8 + kt) * 64 + l) * 8);
        *(fp8frag*)&wlds8[w][kt][l * 8] =
            *(const fp8frag*)(wB8 + ((size_t)((w + 32) * 8 + kt) * 64 + l) * 8);
        *(fp8frag*)&wlds8[w][8 + kt][l * 8] =
            *(const fp8frag*)(wB8 + ((size_t)((w + 48) * 8 + kt) * 64 + l) * 8);
        *(fp8frag*)&wlds8[w][16 + kt][l * 8] =
            *(const fp8frag*)(wB8 + ((size_t)((w + 8) * 8 + kt) * 64 + l) * 8);
    }

    // streamed cc5,6,7 base pointers anchored at kt=4 (imm offsets +/-2048 B)
    const char* pc5 = wB8 + ((size_t)((w + 24) * 8 + 4) * 64 + l) * 8;
    const char* pc6 = wB8 + ((size_t)((w + 40) * 8 + 4) * 64 + l) * 8;
    const char* pc7 = wB8 + ((size_t)((w + 56) * 8 + 4) * 64 + l) * 8;
#define LQ3(D, KT)                                       \
    do {                                                 \
        D[0] = *(const fp8frag*)(pc5 + ((KT) - 4) * 512);\
        D[1] = *(const fp8frag*)(pc6 + ((KT) - 4) * 512);\
        D[2] = *(const fp8frag*)(pc7 + ((KT) - 4) * 512);\
    } while (0)

    __syncthreads();
    if (tid < 16) xb[0][tid] = x[(size_t)(m0 + tid) * TT];

    const float bm = b_mean[0], blv = b_logvar[0];
    const float DS = 1.f / 1024.f;   // descale: w x64 * h x16
    const int arow = l & 15;
    const int ako = 8 * (l >> 4);
    const int r0 = (l >> 4) * 4;
    const bool headwave = (w == 0);
    float c[8];
#pragma unroll
    for (int i = 0; i < 8; ++i) c[i] = 0.f;

    fp8frag sb[3], tb[3];
    LQ3(sb, 0);  // kt0 group for t=0, in flight across the init barrier
    __syncthreads();

#define KTEVEN(KT)                                                              \
    do {                                                                        \
        fp8frag af8 = *(const fp8frag*)&hbuf8[rb][arow][(KT) * 32 + ako];       \
        LQ3(tb, (KT) + 1);                                                      \
        accs[0] = MFMA_FP8(af8, wreg8[KT], accs[0], 0, 0, 0);                   \
        accs[1] = MFMA_FP8(af8, wreg8[8 + (KT)], accs[1], 0, 0, 0);             \
        accs[2] = MFMA_FP8(af8, *(const fp8frag*)&wlds8[w][KT][l * 8], accs[2], 0, 0, 0);        \
        accs[3] = MFMA_FP8(af8, *(const fp8frag*)&wlds8[w][8 + (KT)][l * 8], accs[3], 0, 0, 0);  \
        accs[4] = MFMA_FP8(af8, *(const fp8frag*)&wlds8[w][16 + (KT)][l * 8], accs[4], 0, 0, 0); \
        accs[5] = MFMA_FP8(af8, sb[0], accs[5], 0, 0, 0);                       \
        accs[6] = MFMA_FP8(af8, sb[1], accs[6], 0, 0, 0);                       \
        accs[7] = MFMA_FP8(af8, sb[2], accs[7], 0, 0, 0);                       \
        if (dh) {                                                               \
            bf16x8 afb = *(const bf16x8*)&hbuf[rb][arow][(KT) * 32 + ako];      \
            ah = MFMA_BF16(afb, *(const bf16x8*)&headw[KT][l * 8], ah, 0, 0, 0);\
        }                                                                       \
    } while (0)
#define KTODD(KT, NXT)                                                          \
    do {                                                                        \
        fp8frag af8 = *(const fp8frag*)&hbuf8[rb][arow][(KT) * 32 + ako];       \
        LQ3(sb, NXT);                                                           \
        accs[0] = MFMA_FP8(af8, wreg8[KT], accs[0], 0, 0, 0);                   \
        accs[1] = MFMA_FP8(af8, wreg8[8 + (KT)], accs[1], 0, 0, 0);             \
        accs[2] = MFMA_FP8(af8, *(const fp8frag*)&wlds8[w][KT][l * 8], accs[2], 0, 0, 0);        \
        accs[3] = MFMA_FP8(af8, *(const fp8frag*)&wlds8[w][8 + (KT)][l * 8], accs[3], 0, 0, 0);  \
        accs[4] = MFMA_FP8(af8, *(const fp8frag*)&wlds8[w][16 + (KT)][l * 8], accs[4], 0, 0, 0); \
        accs[5] = MFMA_FP8(af8, tb[0], accs[5], 0, 0, 0);                       \
        accs[6] = MFMA_FP8(af8, tb[1], accs[6], 0, 0, 0);                       \
        accs[7] = MFMA_FP8(af8, tb[2], accs[7], 0, 0, 0);                       \
        if (dh) {                                                               \
            bf16x8 afb = *(const bf16x8*)&hbuf[rb][arow][(KT) * 32 + ako];      \
            ah = MFMA_BF16(afb, *(const bf16x8*)&headw[KT][l * 8], ah, 0, 0, 0);\
        }                                                                       \
    } while (0)

    for (int t = 0; t < TT; ++t) {
        const int pb = t & 1, rb = pb ^ 1;
        const bool dh = headwave && (t >= 1);

        float xn = 0.f;
        if (tid < 16 && t + 1 < TT) xn = x[(size_t)(m0 + tid) * TT + (t + 1)];
        float ev[4] = {0.f, 0.f, 0.f, 0.f};
        if (dh && arow == 0) {
#pragma unroll
            for (int j = 0; j < 4; ++j) ev[j] = eps[(size_t)(m0 + r0 + j) * TT + (t - 1)];
        }

        f32x4 accs[8];
#pragma unroll
        for (int cc = 0; cc < 8; ++cc) accs[cc] = (f32x4){0.f, 0.f, 0.f, 0.f};
        f32x4 ah = {0.f, 0.f, 0.f, 0.f};

        KTEVEN(0);        // consumes sb(kt0), prefetches tb(kt1)
        KTODD(1, 2);
        KTEVEN(2);
        KTODD(3, 4);
        KTEVEN(4);
        KTODD(5, 6);
        KTEVEN(6);
        KTODD(7, 0);      // prefetches sb(kt0) for the NEXT step (weights static)

        // ---- heads epilogue for h_{t-1} (wave 0, all-bf16 path) ----
        if (dh) {
            const int slot = (t - 1) & 15;
#pragma unroll
            for (int j = 0; j < 4; ++j) {
                float lvn = __shfl(ah[j], (l & 48) | 1);  // col-1 lane = logvar
                if (arow == 0) {
                    float mean = ah[j] + bm;
                    float lv = fminf(fmaxf(lvn + blv, -10.f), 2.f);
                    obuf[0][r0 + j][slot] = mean + __expf(0.5f * lv) * ev[j];
                    obuf[1][r0 + j][slot] = mean;
                    obuf[2][r0 + j][slot] = lv;
                }
            }
        }

        // ---- elementwise LSTM cell: accs[p*4+g][j], unit u, row r0+j ----
        {
            float xv[4];
#pragma unroll
            for (int j = 0; j < 4; ++j) xv[j] = xb[t & 1][r0 + j];
#pragma unroll
            for (int p = 0; p < 2; ++p) {
                const int u = 128 * p + 16 * w + arow;
                bf16x4 wv = *(const bf16x4*)&wib[u][0];
                bf16x4 bv = *(const bf16x4*)&bib[u][0];
                const float wi0 = (float)wv[0], wi1 = (float)wv[1],
                            wi2 = (float)wv[2], wi3 = (float)wv[3];
                const float bi0 = (float)bv[0], bi1 = (float)bv[1],
                            bi2 = (float)bv[2], bi3 = (float)bv[3];
#pragma unroll
                for (int j = 0; j < 4; ++j) {
                    float gi = fmaf(accs[p * 4 + 0][j], DS, fmaf(xv[j], wi0, bi0));
                    float gf = fmaf(accs[p * 4 + 1][j], DS, fmaf(xv[j], wi1, bi1));
                    float gg = fmaf(accs[p * 4 + 2][j], DS, fmaf(xv[j], wi2, bi2));
                    float go = fmaf(accs[p * 4 + 3][j], DS, fmaf(xv[j], wi3, bi3));
                    float ia = sg(gi), fa = sg(gf), ga = th(gg), oa = sg(go);
                    float cn = fa * c[p * 4 + j] + ia * ga;
                    c[p * 4 + j] = cn;
                    float hv = oa * th(cn);
                    hbuf[pb][r0 + j][u] = (__bf16)hv;
                    hbuf8[pb][r0 + j][u] =
                        (char)__builtin_amdgcn_cvt_pk_fp8_f32(hv * 16.f, 0.f, 0, false);
                }
            }
        }
        if (tid < 16 && t + 1 < TT) xb[(t + 1) & 1][tid] = xn;

        // ---- coalesced output flush every 16 steps ----
        if ((t & 15) == 0 && t > 0) {
            __syncthreads();  // wave0's obuf writes -> flushing waves
            if (tid < 192) {
                const int o = tid >> 6, rr = (tid >> 2) & 15, q = tid & 3;
                f32x4 v = *(const f32x4*)&obuf[o][rr][q * 4];
                *(f32x4*)(out + (size_t)o * BB * TT + (size_t)(m0 + rr) * TT + (t - 16) + q * 4) = v;
            }
        }
        __syncthreads();
    }

    // ---- tail: head for t = TT-1 (h in hbuf[1], bf16) + final flush ----
    {
        if (headwave) {
            f32x4 ah = {0.f, 0.f, 0.f, 0.f};
            float ev[4] = {0.f, 0.f, 0.f, 0.f};
            if (arow == 0) {
#pragma unroll
                for (int j = 0; j < 4; ++j) ev[j] = eps[(size_t)(m0 + r0 + j) * TT + (TT - 1)];
            }
#pragma unroll
            for (int kt = 0; kt < 8; ++kt) {
                bf16x8 afb = *(const bf16x8*)&hbuf[1][arow][kt * 32 + ako];
                ah = MFMA_BF16(afb, *(const bf16x8*)&headw[kt][l * 8], ah, 0, 0, 0);
            }
#pragma unroll
            for (int j = 0; j < 4; ++j) {
                float lvn = __shfl(ah[j], (l & 48) | 1);
                if (arow == 0) {
                    float mean = ah[j] + bm;
                    float lv = fminf(fmaxf(lvn + blv, -10.f), 2.f);
                    obuf[0][r0 + j][15] = mean + __expf(0.5f * lv) * ev[j];
                    obuf[1][r0 + j][15] = mean;
                    obuf[2][r0 + j][15] = lv;
                }
            }
        }
        __syncthreads();
        if (tid < 192) {
            const int o = tid >> 6, rr = (tid >> 2) & 15, q = tid & 3;
            f32x4 v = *(const f32x4*)&obuf[o][rr][q * 4];
            *(f32x4*)(out + (size_t)o * BB * TT + (size_t)(m0 + rr) * TT + (TT - 16) + q * 4) = v;
        }
    }
#undef KTEVEN
#undef KTODD
#undef LQ3
}

extern "C" void kernel_launch(void* const* d_in, const int* in_sizes, int n_in,
                              void* d_out, int out_size, void* d_ws, size_t ws_size,
                              hipStream_t stream) {
    const float* x = (const float*)d_in[0];
    const float* eps = (const float*)d_in[1];
    const float* w_ih = (const float*)d_in[2];
    const float* w_hh = (const float*)d_in[3];
    const float* b_ih = (const float*)d_in[4];
    const float* b_hh = (const float*)d_in[5];
    const float* w_mean = (const float*)d_in[6];
    const float* b_mean = (const float*)d_in[7];
    const float* w_logvar = (const float*)d_in[8];
    const float* b_logvar = (const float*)d_in[9];

    char* wB8 = (char*)d_ws;  // 256 KB fp8 fragment-ordered weights (x64 scale)

    prep_weights8<<<128, 256, 0, stream>>>(w_hh, wB8);
    lstm_fused<<<256, 512, 0, stream>>>(x, eps, w_ih, b_ih, b_hh, w_mean, b_mean,
                                        w_logvar, b_logvar, wB8, (float*)d_out);
}

// Round 11
// 1279.426 us; speedup vs baseline: 5.9091x; 1.1141x over previous
//
#include <hip/hip_runtime.h>
#include <hip/hip_bf16.h>

#define BB 4096
#define TT 512
#define HH 256

typedef __bf16 bf16x8 __attribute__((ext_vector_type(8)));
typedef float f32x4 __attribute__((ext_vector_type(4)));
typedef long fp8frag;  // 8 x e4m3 in 2 VGPRs

#define MFMA_BF16 __builtin_amdgcn_mfma_f32_16x16x32_bf16
#define MFMA_FP8  __builtin_amdgcn_mfma_f32_16x16x32_fp8_fp8

#if defined(__has_builtin)
#if __has_builtin(__builtin_amdgcn_exp2f)
#define EXP2F(x) __builtin_amdgcn_exp2f(x)
#endif
#endif
#ifndef EXP2F
#define EXP2F(x) __expf((x) * 0.6931471805599453f)
#endif
#define RCPF(x) __builtin_amdgcn_rcpf(x)

#define L2E  1.4426950408889634f
#define TL2E 2.8853900817779268f   // 2*log2e
#define HL2E 0.7213475204444817f   // 0.5*log2e

// w_hh [1024][256] fp32 -> fp8 e4m3 (x64 scale) fragment-ordered buffer:
// frag (ctg,kt), lane l, elem e = 64*w_hh[ctg*16 + (l&15)][kt*32 + 8*(l>>4) + e]
// at wB8[((ctg*8+kt)*64 + l)*8 + e]  (512 B per frag, 256 KB total).
__global__ void prep_weights8(const float* __restrict__ w_hh, char* __restrict__ wB8) {
    int idx = blockIdx.x * blockDim.x + threadIdx.x;
    if (idx >= 64 * 8 * 64) return;
    int l = idx & 63;
    int kt = (idx >> 6) & 7;
    int ctg = idx >> 9;
    int n = ctg * 16 + (l & 15);
    int k0 = kt * 32 + 8 * (l >> 4);
    const float* src = w_hh + n * HH + k0;
    float f[8];
#pragma unroll
    for (int e = 0; e < 8; ++e) f[e] = src[e] * 64.f;
    int lo = __builtin_amdgcn_cvt_pk_fp8_f32(f[0], f[1], 0, false) |
             (__builtin_amdgcn_cvt_pk_fp8_f32(f[2], f[3], 0, false) << 16);
    int hi = __builtin_amdgcn_cvt_pk_fp8_f32(f[4], f[5], 0, false) |
             (__builtin_amdgcn_cvt_pk_fp8_f32(f[6], f[7], 0, false) << 16);
    int2 v; v.x = lo; v.y = hi;
    *(int2*)(wB8 + (size_t)idx * 8) = v;
}

// Activations in exp2 domain: v_exp_f32 IS 2^x; gate pre-activations are
// pre-scaled by log2e (2*log2e for g-gate), so no per-activation multiply.
#define SGg(v) RCPF(1.f + EXP2F(-(v)))                 // sigmoid, v pre-scaled
#define THg(v) (1.f - 2.f * RCPF(EXP2F(v) + 1.f))      // tanh, v pre-scaled 2*l2e

// PIPE-OVERLAP DESIGN (r10 post-mortem: VALU 58% + MFMA 31% + stalls = 100%,
// zero overlap because all waves sit in the same phase). P0 = gate-accs cc0-3;
// P1 = cc4-7 with EW(p0) cells interleaved between kt-pairs so the VALU runs
// under P1's MFMAs. Register law refined: 8-wave blocks get up to 256
// regs/wave (r9/r10: no spill at ~130-150 demand) -> wreg 4 ctgs (64 regs),
// LDS 3 ctgs (96 KB), stream 1 ctg (32 KB/block/step).
__global__ __launch_bounds__(512, 1) void lstm_fused(
    const float* __restrict__ x, const float* __restrict__ eps,
    const float* __restrict__ w_ih, const float* __restrict__ b_ih,
    const float* __restrict__ b_hh, const float* __restrict__ w_mean,
    const float* __restrict__ b_mean, const float* __restrict__ w_logvar,
    const float* __restrict__ b_logvar, const char* __restrict__ wB8,
    float* __restrict__ out)
{
    __shared__ __align__(16) char wlds8[8][24][512];    // 98304 B: cc2,3,6 per wave
    __shared__ __align__(16) __bf16 hbuf[2][16][264];   // 16896 B: bf16 h (heads)
    __shared__ __align__(16) char hbuf8[2][16][264];    // 8448 B: fp8 h*16 (gates)
    __shared__ __align__(16) __bf16 headw[8][512];      // 8192 B
    __shared__ float obuf[2][16][16];                   // 2048 B: mean, logvar
    __shared__ float xb[2][16];                         // 128 B
    // total 134016 B

    const int tid = threadIdx.x;
    const int w = tid >> 6;          // wave 0..7
    const int l = tid & 63;
    const int m0 = blockIdx.x * 16;

    for (int i = tid; i < 2 * 16 * 264; i += 512) (&hbuf[0][0][0])[i] = (__bf16)0.f;
    for (int i = tid; i < 2 * 16 * 264; i += 512) (&hbuf8[0][0][0])[i] = 0;
    // head column-tile (bf16): col 0 = w_mean, col 1 = w_logvar, rest zero
    {
        int kt = tid >> 6, hl = tid & 63;
        int col = hl & 15;
        int k0 = kt * 32 + 8 * (hl >> 4);
        bf16x8 hw;
#pragma unroll
        for (int e = 0; e < 8; ++e) {
            float v = 0.f;
            if (col == 0) v = w_mean[k0 + e];
            else if (col == 1) v = w_logvar[k0 + e];
            hw[e] = (__bf16)v;
        }
        *(bf16x8*)&headw[kt][hl * 8] = hw;
    }

    // wave w owns ctg = w + 8p + 16g for cc = p*4+g.
    // wreg: cc0 (w), cc1 (w+16), cc4 (w+8), cc5 (w+24)
    // LDS : cc2 (w+32), cc3 (w+48), cc6 (w+40)
    // stream: cc7 (w+56), 2-deep single-frag rotation
    fp8frag wreg8[32];
#pragma unroll
    for (int kt = 0; kt < 8; ++kt) {
        wreg8[kt]      = *(const fp8frag*)(wB8 + ((size_t)((w)      * 8 + kt) * 64 + l) * 8);
        wreg8[8 + kt]  = *(const fp8frag*)(wB8 + ((size_t)((w + 16) * 8 + kt) * 64 + l) * 8);
        wreg8[16 + kt] = *(const fp8frag*)(wB8 + ((size_t)((w + 8)  * 8 + kt) * 64 + l) * 8);
        wreg8[24 + kt] = *(const fp8frag*)(wB8 + ((size_t)((w + 24) * 8 + kt) * 64 + l) * 8);
        *(fp8frag*)&wlds8[w][kt][l * 8] =
            *(const fp8frag*)(wB8 + ((size_t)((w + 32) * 8 + kt) * 64 + l) * 8);
        *(fp8frag*)&wlds8[w][8 + kt][l * 8] =
            *(const fp8frag*)(wB8 + ((size_t)((w + 48) * 8 + kt) * 64 + l) * 8);
        *(fp8frag*)&wlds8[w][16 + kt][l * 8] =
            *(const fp8frag*)(wB8 + ((size_t)((w + 40) * 8 + kt) * 64 + l) * 8);
    }
    const char* pc7 = wB8 + ((size_t)((w + 56) * 8 + 4) * 64 + l) * 8;  // kt anchor 4

    const int arow = l & 15;
    const int ako = 8 * (l >> 4);
    const int r0 = (l >> 4) * 4;
    const int u0 = 16 * w + arow, u1 = u0 + 128;

    // per-thread w_ih / fused bias, pre-scaled into the exp2 domain (f32, hoisted)
    float wiA[4], biA[4], wiB[4], biB[4];
#pragma unroll
    for (int g = 0; g < 4; ++g) {
        const float s = (g == 2) ? TL2E : L2E;
        wiA[g] = w_ih[g * 256 + u0] * s;
        biA[g] = (b_ih[g * 256 + u0] + b_hh[g * 256 + u0]) * s;
        wiB[g] = w_ih[g * 256 + u1] * s;
        biB[g] = (b_ih[g * 256 + u1] + b_hh[g * 256 + u1]) * s;
    }
    const float DS1c = L2E / 1024.f;   // acc descale * log2e   (w x64 * h x16)
    const float DS2c = TL2E / 1024.f;  // acc descale * 2*log2e (g-gate)
    const float bm = b_mean[0], blv = b_logvar[0];

    float c[8];
#pragma unroll
    for (int i = 0; i < 8; ++i) c[i] = 0.f;
    const f32x4 Z = {0.f, 0.f, 0.f, 0.f};

    __syncthreads();
    if (tid < 16) xb[0][tid] = x[(size_t)(m0 + tid) * TT];
    fp8frag sbf = *(const fp8frag*)(pc7 - 2048);  // stream kt0 for t=0
    fp8frag tbf;
    __syncthreads();

#define P0KT(KT, RB)                                                            \
    do {                                                                        \
        fp8frag af8_ = *(const fp8frag*)&hbuf8[RB][arow][(KT) * 32 + ako];      \
        a0 = MFMA_FP8(af8_, wreg8[KT], (KT) ? a0 : Z, 0, 0, 0);                 \
        a1 = MFMA_FP8(af8_, wreg8[8 + (KT)], (KT) ? a1 : Z, 0, 0, 0);           \
        a2 = MFMA_FP8(af8_, *(const fp8frag*)&wlds8[w][KT][l * 8], (KT) ? a2 : Z, 0, 0, 0);      \
        a3 = MFMA_FP8(af8_, *(const fp8frag*)&wlds8[w][8 + (KT)][l * 8], (KT) ? a3 : Z, 0, 0, 0);\
    } while (0)

#define P1S(KT, NXT, RB)                                                        \
    do {                                                                        \
        fp8frag af8_ = *(const fp8frag*)&hbuf8[RB][arow][(KT) * 32 + ako];      \
        tbf = *(const fp8frag*)(pc7 + ((NXT) - 4) * 512);                       \
        a4 = MFMA_FP8(af8_, wreg8[16 + (KT)], (KT) ? a4 : Z, 0, 0, 0);          \
        a5 = MFMA_FP8(af8_, wreg8[24 + (KT)], (KT) ? a5 : Z, 0, 0, 0);          \
        a6 = MFMA_FP8(af8_, *(const fp8frag*)&wlds8[w][16 + (KT)][l * 8], (KT) ? a6 : Z, 0, 0, 0);\
        a7 = MFMA_FP8(af8_, sbf, (KT) ? a7 : Z, 0, 0, 0);                       \
    } while (0)

#define P1T(KT, NXT, RB)                                                        \
    do {                                                                        \
        fp8frag af8_ = *(const fp8frag*)&hbuf8[RB][arow][(KT) * 32 + ako];      \
        sbf = *(const fp8frag*)(pc7 + ((NXT) - 4) * 512);                       \
        a4 = MFMA_FP8(af8_, wreg8[16 + (KT)], a4, 0, 0, 0);                     \
        a5 = MFMA_FP8(af8_, wreg8[24 + (KT)], a5, 0, 0, 0);                     \
        a6 = MFMA_FP8(af8_, *(const fp8frag*)&wlds8[w][16 + (KT)][l * 8], a6, 0, 0, 0);          \
        a7 = MFMA_FP8(af8_, tbf, a7, 0, 0, 0);                                  \
    } while (0)

#define EWP0(J, PB)                                                             \
    do {                                                                        \
        float gi_ = fmaf(a0[J], DS1c, fmaf(xv[J], wiA[0], biA[0]));             \
        float gf_ = fmaf(a1[J], DS1c, fmaf(xv[J], wiA[1], biA[1]));             \
        float gg_ = fmaf(a2[J], DS2c, fmaf(xv[J], wiA[2], biA[2]));             \
        float go_ = fmaf(a3[J], DS1c, fmaf(xv[J], wiA[3], biA[3]));             \
        float cn_ = fmaf(SGg(gf_), c[J], SGg(gi_) * THg(gg_));                  \
        c[J] = cn_;                                                             \
        float hv_ = SGg(go_) * THg(cn_ * TL2E);                                 \
        hbuf[PB][r0 + (J)][u0] = (__bf16)hv_;                                   \
        hbuf8[PB][r0 + (J)][u0] =                                               \
            (char)__builtin_amdgcn_cvt_pk_fp8_f32(hv_ * 16.f, 0.f, 0, false);   \
    } while (0)

#define EWP1(J, PB)                                                             \
    do {                                                                        \
        float gi_ = fmaf(a4[J], DS1c, fmaf(xv[J], wiB[0], biB[0]));             \
        float gf_ = fmaf(a5[J], DS1c, fmaf(xv[J], wiB[1], biB[1]));             \
        float gg_ = fmaf(a6[J], DS2c, fmaf(xv[J], wiB[2], biB[2]));             \
        float go_ = fmaf(a7[J], DS1c, fmaf(xv[J], wiB[3], biB[3]));             \
        float cn_ = fmaf(SGg(gf_), c[4 + (J)], SGg(gi_) * THg(gg_));            \
        c[4 + (J)] = cn_;                                                       \
        float hv_ = SGg(go_) * THg(cn_ * TL2E);                                 \
        hbuf[PB][r0 + (J)][u1] = (__bf16)hv_;                                   \
        hbuf8[PB][r0 + (J)][u1] =                                               \
            (char)__builtin_amdgcn_cvt_pk_fp8_f32(hv_ * 16.f, 0.f, 0, false);   \
    } while (0)

#define HEADS(RB, SLOT)                                                         \
    do {                                                                        \
        f32x4 ah_;                                                              \
        {                                                                       \
            bf16x8 afb_ = *(const bf16x8*)&hbuf[RB][arow][0 * 32 + ako];        \
            ah_ = MFMA_BF16(afb_, *(const bf16x8*)&headw[0][l * 8], Z, 0, 0, 0);\
        }                                                                       \
        _Pragma("unroll")                                                       \
        for (int kt_ = 1; kt_ < 8; ++kt_) {                                     \
            bf16x8 afb_ = *(const bf16x8*)&hbuf[RB][arow][kt_ * 32 + ako];      \
            ah_ = MFMA_BF16(afb_, *(const bf16x8*)&headw[kt_][l * 8], ah_, 0, 0, 0);\
        }                                                                       \
        _Pragma("unroll")                                                       \
        for (int j_ = 0; j_ < 4; ++j_) {                                        \
            float lvn_ = __shfl(ah_[j_], (l & 48) | 1);                         \
            if (arow == 0) {                                                    \
                obuf[0][r0 + j_][SLOT] = ah_[j_] + bm;                          \
                obuf[1][r0 + j_][SLOT] = fminf(fmaxf(lvn_ + blv, -10.f), 2.f);  \
            }                                                                   \
        }                                                                       \
    } while (0)

#define FLUSH(T0)                                                               \
    do {                                                                        \
        if (tid < 192) {                                                        \
            const int o_ = tid >> 6, rr_ = (tid >> 2) & 15, q_ = tid & 3;       \
            f32x4 mv_ = *(const f32x4*)&obuf[0][rr_][q_ * 4];                   \
            f32x4 lv_ = *(const f32x4*)&obuf[1][rr_][q_ * 4];                   \
            const size_t base_ = (size_t)(m0 + rr_) * TT + (T0) + q_ * 4;       \
            if (o_ == 0) {                                                      \
                f32x4 e_ = *(const f32x4*)&eps[base_];                          \
                f32x4 s_;                                                       \
                _Pragma("unroll")                                               \
                for (int k_ = 0; k_ < 4; ++k_)                                  \
                    s_[k_] = fmaf(EXP2F(lv_[k_] * HL2E), e_[k_], mv_[k_]);      \
                *(f32x4*)&out[base_] = s_;                                      \
            } else if (o_ == 1) {                                               \
                *(f32x4*)&out[(size_t)BB * TT + base_] = mv_;                   \
            } else {                                                            \
                *(f32x4*)&out[2 * (size_t)BB * TT + base_] = lv_;               \
            }                                                                   \
        }                                                                       \
    } while (0)

#define STEP(PB, RB)                                                            \
    do {                                                                        \
        const int tt = t0 + (PB);                                               \
        float xn = 0.f;                                                         \
        if (tid < 16 && tt + 1 < TT) xn = x[(size_t)(m0 + tid) * TT + (tt + 1)];\
        float xv[4];                                                            \
        xv[0] = xb[PB][r0];     xv[1] = xb[PB][r0 + 1];                         \
        xv[2] = xb[PB][r0 + 2]; xv[3] = xb[PB][r0 + 3];                         \
        f32x4 a0, a1, a2, a3, a4, a5, a6, a7;                                   \
        P0KT(0, RB); P0KT(1, RB); P0KT(2, RB); P0KT(3, RB);                     \
        P0KT(4, RB); P0KT(5, RB); P0KT(6, RB); P0KT(7, RB);                     \
        P1S(0, 1, RB); P1T(1, 2, RB); EWP0(0, PB);                              \
        P1S(2, 3, RB); P1T(3, 4, RB); EWP0(1, PB);                              \
        P1S(4, 5, RB); P1T(5, 6, RB); EWP0(2, PB);                              \
        P1S(6, 7, RB); P1T(7, 0, RB); EWP0(3, PB);                              \
        if (w == 7 && tt >= 1) { HEADS(RB, (tt - 1) & 15); }                    \
        EWP1(0, PB); EWP1(1, PB); EWP1(2, PB); EWP1(3, PB);                     \
        if (tid < 16 && tt + 1 < TT) xb[(PB) ^ 1][tid] = xn;                    \
        if ((PB) == 0 && tt > 0 && (tt & 15) == 0) {                            \
            __syncthreads();                                                    \
            FLUSH(tt - 16);                                                     \
        }                                                                       \
        __syncthreads();                                                        \
    } while (0)

    for (int t0 = 0; t0 < TT; t0 += 2) {
        STEP(0, 1);
        STEP(1, 0);
    }

    // ---- tail: head for h_{TT-1} (in hbuf[1]) + final flush ----
    if (w == 7) { HEADS(1, 15); }
    __syncthreads();
    FLUSH(TT - 16);

#undef P0KT
#undef P1S
#undef P1T
#undef EWP0
#undef EWP1
#undef HEADS
#undef FLUSH
#undef STEP
}

extern "C" void kernel_launch(void* const* d_in, const int* in_sizes, int n_in,
                              void* d_out, int out_size, void* d_ws, size_t ws_size,
                              hipStream_t stream) {
    const float* x = (const float*)d_in[0];
    const float* eps = (const float*)d_in[1];
    const float* w_ih = (const float*)d_in[2];
    const float* w_hh = (const float*)d_in[3];
    const float* b_ih = (const float*)d_in[4];
    const float* b_hh = (const float*)d_in[5];
    const float* w_mean = (const float*)d_in[6];
    const float* b_mean = (const float*)d_in[7];
    const float* w_logvar = (const float*)d_in[8];
    const float* b_logvar = (const float*)d_in[9];

    char* wB8 = (char*)d_ws;  // 256 KB fp8 fragment-ordered weights (x64 scale)

    prep_weights8<<<128, 256, 0, stream>>>(w_hh, wB8);
    lstm_fused<<<256, 512, 0, stream>>>(x, eps, w_ih, b_ih, b_hh, w_mean, b_mean,
                                        w_logvar, b_logvar, wB8, (float*)d_out);
}

// Round 12
// 1067.829 us; speedup vs baseline: 7.0800x; 1.1982x over previous
//
#include <hip/hip_runtime.h>
#include <hip/hip_bf16.h>

#define BB 4096
#define TT 512
#define HH 256

typedef __bf16 bf16x8 __attribute__((ext_vector_type(8)));
typedef __bf16 bf16x4 __attribute__((ext_vector_type(4)));
typedef float f32x4 __attribute__((ext_vector_type(4)));
typedef long fp8frag;  // 8 x e4m3 in 2 VGPRs

#define MFMA_BF16 __builtin_amdgcn_mfma_f32_16x16x32_bf16
#define MFMA_FP8  __builtin_amdgcn_mfma_f32_16x16x32_fp8_fp8

#if defined(__has_builtin)
#if __has_builtin(__builtin_amdgcn_exp2f)
#define EXP2F(x) __builtin_amdgcn_exp2f(x)
#endif
#endif
#ifndef EXP2F
#define EXP2F(x) __expf((x) * 0.6931471805599453f)
#endif
#define RCPF(x) __builtin_amdgcn_rcpf(x)

#define L2E  1.4426950408889634f
#define TL2E 2.8853900817779268f   // 2*log2e
#define HL2E 0.7213475204444817f   // 0.5*log2e

// OPERAND-SWAP LAYOUT (round-12): A = W (fp8, x64), B = h (fp8, x16).
// A-frag and B-frag have identical per-lane layouts (lane l: 8 k-contiguous
// elems at non-k index l&15), so W frags keep the same storage; the MFMA
// output is now D[unit][batch]: col=lane&15=batch row, row=(lane>>4)*4+j =
// 4 CONSECUTIVE units -> contiguous h-writes, shfl-free heads.
// Extended K = 288: k=256 -> x (x16 fp8 on B / w_ih x64 on A), k=257 -> 1
// (=16 fp8 on B / bias x64 on A), k>=258 zeros. 9 k-tiles.
// wB8[((ctg*9 + kt)*64 + l)*8 + e], 64 ctg, 294912 B.
__global__ void prep_weights8(const float* __restrict__ w_hh, const float* __restrict__ w_ih,
                              const float* __restrict__ b_ih, const float* __restrict__ b_hh,
                              char* __restrict__ wB8) {
    int idx = blockIdx.x * blockDim.x + threadIdx.x;
    if (idx >= 64 * 9 * 64) return;
    int l = idx & 63;
    int kt = (idx >> 6) % 9;
    int ctg = idx / (9 * 64);
    int n = ctg * 16 + (l & 15);
    int k0 = kt * 32 + 8 * (l >> 4);
    float f[8];
#pragma unroll
    for (int e = 0; e < 8; ++e) {
        int k = k0 + e;
        float v = 0.f;
        if (k < 256) v = w_hh[n * HH + k];
        else if (k == 256) v = w_ih[n];
        else if (k == 257) v = b_ih[n] + b_hh[n];
        f[e] = v * 64.f;
    }
    int lo = __builtin_amdgcn_cvt_pk_fp8_f32(f[0], f[1], 0, false);
    lo = __builtin_amdgcn_cvt_pk_fp8_f32(f[2], f[3], lo, true);
    int hi = __builtin_amdgcn_cvt_pk_fp8_f32(f[4], f[5], 0, false);
    hi = __builtin_amdgcn_cvt_pk_fp8_f32(f[6], f[7], hi, true);
    int2 v; v.x = lo; v.y = hi;
    *(int2*)(wB8 + (size_t)idx * 8) = v;
}

// exp2-domain activations (v_exp_f32 IS 2^x); inputs pre-scaled by log2e.
#define SGg(v) RCPF(1.f + EXP2F(-(v)))
#define THg(v) (1.f - 2.f * RCPF(EXP2F(v) + 1.f))

__global__ __launch_bounds__(512, 1) void lstm_fused(
    const float* __restrict__ x, const float* __restrict__ eps,
    const float* __restrict__ w_mean, const float* __restrict__ b_mean,
    const float* __restrict__ w_logvar, const float* __restrict__ b_logvar,
    const char* __restrict__ wB8, float* __restrict__ out)
{
    __shared__ __align__(16) char wlds8[8][27][512];    // 110592 B: cc2,cc3,cc6
    __shared__ __align__(16) __bf16 hbuf[2][16][296];   // 18944 B: bf16 h|x|1 (heads)
    __shared__ __align__(16) char hbuf8[2][16][296];    // 9472 B: fp8 (h|x)*16, 1*16
    __shared__ __align__(16) __bf16 headw[9][512];      // 9216 B
    __shared__ float obuf[2][16][16];                   // 2048 B: mean, logvar(clipped)
    // total 150272 B

    const int tid = threadIdx.x;
    const int w = tid >> 6;          // wave 0..7
    const int l = tid & 63;
    const int m0 = blockIdx.x * 16;

    for (int i = tid; i < 2 * 16 * 296; i += 512) (&hbuf[0][0][0])[i] = (__bf16)0.f;
    for (int i = tid; i < 2 * 16 * 296; i += 512) (&hbuf8[0][0][0])[i] = 0;
    // headw A-frags: row 0 = w_mean, row 1 = w_logvar (k=257 -> biases)
    for (int i = tid; i < 9 * 64; i += 512) {
        int kt = i >> 6, hl = i & 63;
        int col = hl & 15;
        int k0 = kt * 32 + 8 * (hl >> 4);
        bf16x8 hw;
#pragma unroll
        for (int e = 0; e < 8; ++e) {
            int k = k0 + e;
            float v = 0.f;
            if (k < 256) {
                if (col == 0) v = w_mean[k];
                else if (col == 1) v = w_logvar[k];
            } else if (k == 257) {
                if (col == 0) v = b_mean[0];
                else if (col == 1) v = b_logvar[0];
            }
            hw[e] = (__bf16)v;
        }
        *(bf16x8*)&headw[kt][hl * 8] = hw;
    }

    // wave w owns ctg = w + 8p + 16g for cc = p*4+g.
    // wreg: cc0 (w), cc1 (w+16), cc4 (w+8), cc5 (w+24)  [36 frags, 72 regs]
    // LDS : cc2 (w+32), cc3 (w+48), cc6 (w+40)          [27 frags/wave]
    // stream: cc7 (w+56)                                 [9 frags/step]
    fp8frag wreg8[36];
#pragma unroll
    for (int kt = 0; kt < 9; ++kt) {
        wreg8[kt]      = *(const fp8frag*)(wB8 + ((size_t)((w)      * 9 + kt) * 64 + l) * 8);
        wreg8[9 + kt]  = *(const fp8frag*)(wB8 + ((size_t)((w + 16) * 9 + kt) * 64 + l) * 8);
        wreg8[18 + kt] = *(const fp8frag*)(wB8 + ((size_t)((w + 8)  * 9 + kt) * 64 + l) * 8);
        wreg8[27 + kt] = *(const fp8frag*)(wB8 + ((size_t)((w + 24) * 9 + kt) * 64 + l) * 8);
        *(fp8frag*)&wlds8[w][kt][l * 8] =
            *(const fp8frag*)(wB8 + ((size_t)((w + 32) * 9 + kt) * 64 + l) * 8);
        *(fp8frag*)&wlds8[w][9 + kt][l * 8] =
            *(const fp8frag*)(wB8 + ((size_t)((w + 48) * 9 + kt) * 64 + l) * 8);
        *(fp8frag*)&wlds8[w][18 + kt][l * 8] =
            *(const fp8frag*)(wB8 + ((size_t)((w + 40) * 9 + kt) * 64 + l) * 8);
    }
    const char* pc7 = wB8 + ((size_t)((w + 56) * 9 + 4) * 64 + l) * 8;  // kt anchor 4

    const int arow = l & 15;
    const int ako = 8 * (l >> 4);
    const int u0 = 16 * w + ((l >> 4) << 2);   // 4 consecutive units
    const int u1 = u0 + 128;

    const float DS1c = L2E / 1024.f;   // acc descale * log2e
    const float DS2c = TL2E / 1024.f;  // acc descale * 2*log2e (g-gate)

    float c[8];
#pragma unroll
    for (int i = 0; i < 8; ++i) c[i] = 0.f;
    const f32x4 Z = {0.f, 0.f, 0.f, 0.f};

    __syncthreads();
    if (tid < 16) {
        hbuf[0][tid][257] = (__bf16)1.0f;
        hbuf[1][tid][257] = (__bf16)1.0f;
        hbuf8[0][tid][257] = (char)__builtin_amdgcn_cvt_pk_fp8_f32(16.f, 0.f, 0, false);
        hbuf8[1][tid][257] = (char)__builtin_amdgcn_cvt_pk_fp8_f32(16.f, 0.f, 0, false);
        float x0 = x[(size_t)(m0 + tid) * TT];
        hbuf[1][tid][256] = (__bf16)x0;                 // rb of t=0 is buf 1
        hbuf8[1][tid][256] = (char)__builtin_amdgcn_cvt_pk_fp8_f32(x0 * 16.f, 0.f, 0, false);
    }
    fp8frag sbf = *(const fp8frag*)(pc7 - 2048);  // stream kt0 for t=0
    fp8frag tbf;
    __syncthreads();

#define P0KT(KT, RB)                                                            \
    do {                                                                        \
        fp8frag hf_ = *(const fp8frag*)&hbuf8[RB][arow][(KT) * 32 + ako];       \
        a0 = MFMA_FP8(wreg8[KT], hf_, (KT) ? a0 : Z, 0, 0, 0);                  \
        a1 = MFMA_FP8(wreg8[9 + (KT)], hf_, (KT) ? a1 : Z, 0, 0, 0);            \
        a2 = MFMA_FP8(*(const fp8frag*)&wlds8[w][KT][l * 8], hf_, (KT) ? a2 : Z, 0, 0, 0);       \
        a3 = MFMA_FP8(*(const fp8frag*)&wlds8[w][9 + (KT)][l * 8], hf_, (KT) ? a3 : Z, 0, 0, 0); \
    } while (0)

#define P1KT(KT, NXT, RB, USE, PF)                                              \
    do {                                                                        \
        fp8frag hf_ = *(const fp8frag*)&hbuf8[RB][arow][(KT) * 32 + ako];       \
        PF = *(const fp8frag*)(pc7 + ((NXT) - 4) * 512);                        \
        a4 = MFMA_FP8(wreg8[18 + (KT)], hf_, (KT) ? a4 : Z, 0, 0, 0);           \
        a5 = MFMA_FP8(wreg8[27 + (KT)], hf_, (KT) ? a5 : Z, 0, 0, 0);           \
        a6 = MFMA_FP8(*(const fp8frag*)&wlds8[w][18 + (KT)][l * 8], hf_, (KT) ? a6 : Z, 0, 0, 0);\
        a7 = MFMA_FP8(USE, hf_, (KT) ? a7 : Z, 0, 0, 0);                        \
    } while (0)

#define EWP0C(J)                                                                \
    do {                                                                        \
        float gi_ = a0[J] * DS1c, gf_ = a1[J] * DS1c;                           \
        float gg_ = a2[J] * DS2c, go_ = a3[J] * DS1c;                           \
        float cn_ = fmaf(SGg(gf_), c[J], SGg(gi_) * THg(gg_));                  \
        c[J] = cn_;                                                             \
        hA[J] = SGg(go_) * THg(cn_ * TL2E);                                     \
    } while (0)

#define EWP1C(J)                                                                \
    do {                                                                        \
        float gi_ = a4[J] * DS1c, gf_ = a5[J] * DS1c;                           \
        float gg_ = a6[J] * DS2c, go_ = a7[J] * DS1c;                           \
        float cn_ = fmaf(SGg(gf_), c[4 + (J)], SGg(gi_) * THg(gg_));            \
        c[4 + (J)] = cn_;                                                       \
        hB[J] = SGg(go_) * THg(cn_ * TL2E);                                     \
    } while (0)

#define WRH(PB, HV, U)                                                          \
    do {                                                                        \
        bf16x4 hb_ = {(__bf16)HV[0], (__bf16)HV[1], (__bf16)HV[2], (__bf16)HV[3]};\
        *(bf16x4*)&hbuf[PB][arow][U] = hb_;                                     \
        int pk_ = __builtin_amdgcn_cvt_pk_fp8_f32(HV[0] * 16.f, HV[1] * 16.f, 0, false);\
        pk_ = __builtin_amdgcn_cvt_pk_fp8_f32(HV[2] * 16.f, HV[3] * 16.f, pk_, true);  \
        *(int*)&hbuf8[PB][arow][U] = pk_;                                       \
    } while (0)

#define HEADS(RB, SLOT)                                                         \
    do {                                                                        \
        f32x4 ah_;                                                              \
        {                                                                       \
            bf16x8 hb_ = *(const bf16x8*)&hbuf[RB][arow][0 * 32 + ako];         \
            ah_ = MFMA_BF16(*(const bf16x8*)&headw[0][l * 8], hb_, Z, 0, 0, 0); \
        }                                                                       \
        _Pragma("unroll")                                                       \
        for (int kt_ = 1; kt_ < 9; ++kt_) {                                     \
            bf16x8 hb_ = *(const bf16x8*)&hbuf[RB][arow][kt_ * 32 + ako];       \
            ah_ = MFMA_BF16(*(const bf16x8*)&headw[kt_][l * 8], hb_, ah_, 0, 0, 0);\
        }                                                                       \
        if (l < 16) {                                                           \
            obuf[0][l][SLOT] = ah_[0];                                          \
            obuf[1][l][SLOT] = fminf(fmaxf(ah_[1], -10.f), 2.f);                \
        }                                                                       \
    } while (0)

#define FLUSH(T0)                                                               \
    do {                                                                        \
        if (tid < 192) {                                                        \
            const int o_ = tid >> 6, rr_ = (tid >> 2) & 15, q_ = tid & 3;       \
            f32x4 mv_ = *(const f32x4*)&obuf[0][rr_][q_ * 4];                   \
            f32x4 lv_ = *(const f32x4*)&obuf[1][rr_][q_ * 4];                   \
            const size_t base_ = (size_t)(m0 + rr_) * TT + (T0) + q_ * 4;       \
            if (o_ == 0) {                                                      \
                f32x4 e_ = *(const f32x4*)&eps[base_];                          \
                f32x4 s_;                                                       \
                _Pragma("unroll")                                               \
                for (int k_ = 0; k_ < 4; ++k_)                                  \
                    s_[k_] = fmaf(EXP2F(lv_[k_] * HL2E), e_[k_], mv_[k_]);      \
                *(f32x4*)&out[base_] = s_;                                      \
            } else if (o_ == 1) {                                               \
                *(f32x4*)&out[(size_t)BB * TT + base_] = mv_;                   \
            } else {                                                            \
                *(f32x4*)&out[2 * (size_t)BB * TT + base_] = lv_;               \
            }                                                                   \
        }                                                                       \
    } while (0)

#define STEP(PB, RB, BA, BX)                                                    \
    do {                                                                        \
        const int tt = t0 + (PB);                                               \
        float xn = 0.f;                                                         \
        if (tid < 16 && tt + 1 < TT) xn = x[(size_t)(m0 + tid) * TT + (tt + 1)];\
        f32x4 a0, a1, a2, a3, a4, a5, a6, a7;                                   \
        float hA[4], hB[4];                                                     \
        P0KT(0, RB); P0KT(1, RB); P0KT(2, RB); P0KT(3, RB); P0KT(4, RB);        \
        P0KT(5, RB); P0KT(6, RB); P0KT(7, RB); P0KT(8, RB);                     \
        P1KT(0, 1, RB, BA, BX); P1KT(1, 2, RB, BX, BA); EWP0C(0);               \
        P1KT(2, 3, RB, BA, BX); P1KT(3, 4, RB, BX, BA); EWP0C(1);               \
        P1KT(4, 5, RB, BA, BX); P1KT(5, 6, RB, BX, BA); EWP0C(2);               \
        P1KT(6, 7, RB, BA, BX); P1KT(7, 8, RB, BX, BA); EWP0C(3);               \
        P1KT(8, 0, RB, BA, BX);                                                 \
        WRH(PB, hA, u0);                                                        \
        if (w == 7 && tt >= 1) { HEADS(RB, (tt - 1) & 15); }                    \
        EWP1C(0); EWP1C(1); EWP1C(2); EWP1C(3);                                 \
        WRH(PB, hB, u1);                                                        \
        if (tid < 16 && tt + 1 < TT) {                                          \
            hbuf[PB][tid][256] = (__bf16)xn;                                    \
            hbuf8[PB][tid][256] =                                               \
                (char)__builtin_amdgcn_cvt_pk_fp8_f32(xn * 16.f, 0.f, 0, false);\
        }                                                                       \
        if ((PB) == 0 && tt > 0 && (tt & 15) == 0) {                            \
            __syncthreads();                                                    \
            FLUSH(tt - 16);                                                     \
        }                                                                       \
        __syncthreads();                                                        \
    } while (0)

    for (int t0 = 0; t0 < TT; t0 += 2) {
        STEP(0, 1, sbf, tbf);
        STEP(1, 0, tbf, sbf);
    }

    // ---- tail: head for h_{TT-1} (in hbuf[1]) + final flush ----
    if (w == 7) { HEADS(1, 15); }
    __syncthreads();
    FLUSH(TT - 16);

#undef P0KT
#undef P1KT
#undef EWP0C
#undef EWP1C
#undef WRH
#undef HEADS
#undef FLUSH
#undef STEP
}

extern "C" void kernel_launch(void* const* d_in, const int* in_sizes, int n_in,
                              void* d_out, int out_size, void* d_ws, size_t ws_size,
                              hipStream_t stream) {
    const float* x = (const float*)d_in[0];
    const float* eps = (const float*)d_in[1];
    const float* w_ih = (const float*)d_in[2];
    const float* w_hh = (const float*)d_in[3];
    const float* b_ih = (const float*)d_in[4];
    const float* b_hh = (const float*)d_in[5];
    const float* w_mean = (const float*)d_in[6];
    const float* b_mean = (const float*)d_in[7];
    const float* w_logvar = (const float*)d_in[8];
    const float* b_logvar = (const float*)d_in[9];

    char* wB8 = (char*)d_ws;  // 288 KB fp8 A-frag weights (x64, K=288 fold)

    prep_weights8<<<144, 256, 0, stream>>>(w_hh, w_ih, b_ih, b_hh, wB8);
    lstm_fused<<<256, 512, 0, stream>>>(x, eps, w_mean, b_mean, w_logvar, b_logvar,
                                        wB8, (float*)d_out);
}